// Round 17
// baseline (1258.261 us; speedup 1.0000x reference)
//
#include <hip/hip_runtime.h>
#include <cstddef>
#include <cstdint>

#define NH 9
#define QLD 16  // compact xu row stride in fp16 (32B, line-aligned rows)

typedef _Float16 f16x8 __attribute__((ext_vector_type(8)));
typedef _Float16 f16x4 __attribute__((ext_vector_type(4)));
typedef _Float16 f16x2 __attribute__((ext_vector_type(2)));
typedef float f32x4 __attribute__((ext_vector_type(4)));

static const int cN1 = 100000, cN2 = 25000, cN3 = 6250;
static const int cE1 = 1200000, cE2 = 300000, cE3 = 75000;

static inline unsigned ceil_div(size_t a, size_t b) { return (unsigned)((a + b - 1) / b); }

// ---------------- pre-packed B panel: WT[n][Kpad] fp16, cols = [W | Wself | u] ----------------
struct PackArgs {
    const float* W[8];
    const float* c[8];
    const float* u[8];
    int K[8], OUT[8], Kpad[8], base[8];
    int total;
};

__global__ void pack_b_all(PackArgs a, _Float16* __restrict__ wt)
{
    int i = blockIdx.x * 256 + threadIdx.x;
    if (i >= a.total) return;
    int li = 0;
#pragma unroll
    for (int j = 1; j < 8; ++j) li += (i >= a.base[j]);
    int r = i - a.base[li];
    int Kp = a.Kpad[li], K = a.K[li], OUT = a.OUT[li];
    int NC = NH * OUT, NCO = NC + OUT;
    int n = r / Kp, k = r % Kp;
    float v = 0.f;
    if (k < K) {
        if (n < NC) v = a.W[li][(size_t)k * NC + n];
        else if (n < NCO) {
            const float* cv = a.c[li];
            float t[NH], m = -1e30f;
#pragma unroll
            for (int h = 0; h < NH; ++h) { t[h] = cv[h]; m = fmaxf(m, t[h]); }
            float den = 0.f;
#pragma unroll
            for (int h = 0; h < NH; ++h) { t[h] = __expf(t[h] - m); den += t[h]; }
            int o = n - NC;
            float acc = 0.f;
#pragma unroll
            for (int h = 0; h < NH; ++h) acc += t[h] * a.W[li][(size_t)k * NC + h * OUT + o];
            v = acc / den;
        } else {
            v = a.u[li][(size_t)k * NH + (n - NCO)];
        }
    }
    wt[i] = (_Float16)v;
}

// ---------------- merged f16 MFMA GEMM: C row = [ xW (NC) | x*Wself (OUT) | xu (9) | pad ] ----------------
// A is fp32 or fp16 (template); fp16 path uses direct 16B loads -> conflict-free LDS staging.
// Optional ridx gathers A rows. xu tail also copied to compact XUH.
// Fragment layout verified numerically (fc_head2, rounds 3-16).
template <typename AT>
__global__ __launch_bounds__(256) void gemm_merged(
    const AT* __restrict__ A, int lda, const int* __restrict__ ridx,
    const _Float16* __restrict__ WT, int kpad,
    _Float16* __restrict__ C, _Float16* __restrict__ xuh,
    int M, int K, int NC, int OUT)
{
    const int N = NC + OUT + NH;
    const int NCO = NC + OUT;
    const int ldc = NCO + 16;
    const int BM = 64, BK = 32, LK = 40;
    __shared__ _Float16 As[BM][LK];
    __shared__ _Float16 Bs[64][LK];  // transposed: Bs[n][k]
    const int tid = threadIdx.x;
    const int row0 = blockIdx.y * BM, col0 = blockIdx.x * 64;
    const int lane = tid & 63, wv = tid >> 6;
    const int g = lane >> 4, r16 = lane & 15;
    const int wr = wv >> 1, wc = wv & 1;
    f32x4 acc[2][2] = {};
    for (int k0 = 0; k0 < K; k0 += BK) {
        if constexpr (sizeof(AT) == 2) {
            int r = tid >> 2, c0 = (tid & 3) * 8;
            int gr = row0 + r, gk = k0 + c0;
            f16x8 h = {};
            if (gr < M) {
                int ar = ridx ? ridx[gr] : gr;
                h = *(const f16x8*)((const _Float16*)A + (size_t)ar * lda + gk);
            }
            *(f16x8*)&As[r][c0] = h;
        } else {
            for (int l = tid; l < 512; l += 256) {
                int r = l >> 3, c0 = (l & 7) * 4;
                int gr = row0 + r, gk = k0 + c0;
                float v0 = 0.f, v1 = 0.f, v2 = 0.f, v3 = 0.f;
                if (gr < M) {
                    int ar = ridx ? ridx[gr] : gr;
                    const float* ap = (const float*)A + (size_t)ar * lda + gk;
                    if (gk < K)     v0 = ap[0];
                    if (gk + 1 < K) v1 = ap[1];
                    if (gk + 2 < K) v2 = ap[2];
                    if (gk + 3 < K) v3 = ap[3];
                }
                f16x4 h;
                h[0] = (_Float16)v0; h[1] = (_Float16)v1; h[2] = (_Float16)v2; h[3] = (_Float16)v3;
                *(f16x4*)&As[r][c0] = h;
            }
        }
        {
            int nn = tid >> 2, c0 = (tid & 3) * 8;
            int gn = col0 + nn, gk = k0 + c0;
            f16x8 h = {};
            if (gn < N) h = *(const f16x8*)(WT + (size_t)gn * kpad + gk);
            *(f16x8*)&Bs[nn][c0] = h;
        }
        __syncthreads();
        f16x8 af[2], bf[2];
#pragma unroll
        for (int i = 0; i < 2; ++i) af[i] = *(const f16x8*)&As[wr * 32 + i * 16 + r16][g * 8];
#pragma unroll
        for (int j = 0; j < 2; ++j) bf[j] = *(const f16x8*)&Bs[wc * 32 + j * 16 + r16][g * 8];
#pragma unroll
        for (int i = 0; i < 2; ++i)
#pragma unroll
            for (int j = 0; j < 2; ++j)
                acc[i][j] = __builtin_amdgcn_mfma_f32_16x16x32_f16(af[i], bf[j], acc[i][j], 0, 0, 0);
        __syncthreads();
    }
#pragma unroll
    for (int i = 0; i < 2; ++i)
#pragma unroll
        for (int j = 0; j < 2; ++j) {
            int gc = col0 + wc * 32 + j * 16 + r16;
            if (gc >= N) continue;
            int tcol = gc - NCO;
#pragma unroll
            for (int rr = 0; rr < 4; ++rr) {
                int gr = row0 + wr * 32 + i * 16 + g * 4 + rr;
                if (gr >= M) continue;
                _Float16 val = (_Float16)acc[i][j][rr];
                C[(size_t)gr * ldc + gc] = val;
                if (tcol >= 0) xuh[(size_t)gr * QLD + tcol] = val;
            }
        }
}

// ---------------- counting / scan / segment-fill / binned two-pass scatter ----------------
__global__ void count_idx(const int* __restrict__ idx, int n, int* __restrict__ cnt)
{
    int i = blockIdx.x * 256 + threadIdx.x;
    if (i < n) atomicAdd(&cnt[idx[i]], 1);
}

// src-degree + dst-degree + src-bucket counts in one edge pass
__global__ void count_b3(const int* __restrict__ src, const int* __restrict__ dst, int E,
                         int* __restrict__ scnt, int* __restrict__ dcnt,
                         int* __restrict__ bcnt, int shift)
{
    int i = blockIdx.x * 256 + threadIdx.x;
    if (i >= E) return;
    int s = src[i];
    atomicAdd(&scnt[s], 1);
    atomicAdd(&dcnt[dst[i]], 1);
    atomicAdd(&bcnt[s >> shift], 1);
}

__global__ __launch_bounds__(1024) void scan1(const int* __restrict__ in, int* __restrict__ out,
                                              int* __restrict__ part, int n)
{
    __shared__ int wsum[16];
    const int tid = threadIdx.x, lane = tid & 63, wv = tid >> 6;
    int i = blockIdx.x * 1024 + tid;
    int v = (i < n) ? in[i] : 0;
    int acc = v;
#pragma unroll
    for (int off = 1; off < 64; off <<= 1) {
        int t = __shfl_up(acc, off);
        if (lane >= off) acc += t;
    }
    if (lane == 63) wsum[wv] = acc;
    __syncthreads();
    if (wv == 0 && lane < 16) {
        int s = wsum[lane];
        int a2 = s;
#pragma unroll
        for (int off = 1; off < 16; off <<= 1) {
            int t = __shfl_up(a2, off);
            if (lane >= off) a2 += t;
        }
        wsum[lane] = a2 - s;
    }
    __syncthreads();
    int ex = wsum[wv] + acc - v;
    if (i < n) out[i] = ex;
    if (part && tid == 1023) part[blockIdx.x] = ex + v;
}

__global__ void scan_add(int* __restrict__ out, const int* __restrict__ part, int n)
{
    int i = blockIdx.x * 1024 + threadIdx.x;
    if (i < n) out[i] += part[blockIdx.x];
}

__global__ void fill_src(const int* __restrict__ soffB, const int* __restrict__ scnt,
                         int* __restrict__ srcs, int n, int ebias)
{
    int i = blockIdx.x * 256 + threadIdx.x;
    if (i >= n) return;
    int b = soffB[i] - ebias, c = scnt[i];
    for (int k = 0; k < c; ++k) srcs[b + k] = i;
}

// pass 1: bin edges by src>>shift. Active write set = #buckets lines (~200KB, L2-resident)
// -> writes merge to ~payload (the r16 scatter's 12x line amplification came from ~1M open lines).
__global__ void bin_pass1(const int* __restrict__ src, const int* __restrict__ dst, int E,
                          const int* __restrict__ boff, int* __restrict__ bcur,
                          int2* __restrict__ tmp, int shift)
{
    int e = blockIdx.x * 256 + threadIdx.x;
    if (e >= E) return;
    int s = src[e];
    int b = s >> shift;
    int p = boff[b] + atomicAdd(&bcur[b], 1);
    tmp[p] = make_int2(s, dst[e]);
}

// pass 2: stream bucket-sorted TMP (coalesced read); exact src-position + dst-CSR slot; write
// erec[ps] -- each bucket's writes span a ~12KB erec window processed in grid order (L2-merged).
__global__ void bin_pass2(const int2* __restrict__ tmp, int E,
                          const int* __restrict__ soffB, int* __restrict__ curs,
                          const int* __restrict__ doff, int* __restrict__ curd,
                          int2* __restrict__ erec, int ebias)
{
    int e = blockIdx.x * 256 + threadIdx.x;
    if (e >= E) return;
    int2 rec = tmp[e];
    int s = rec.x, d = rec.y;
    int ps = soffB[s] - ebias + atomicAdd(&curs[s], 1);
    int pd = doff[d] + atomicAdd(&curd[d], 1);
    erec[ps] = make_int2(d, pd);
}

// ---------------- Phase 1: per-edge q (inline softmax) + 9-head collapse -> MSG[pd] ----------------
// src-sorted compute (xwa row L1-hot); MSG write random but full 64-256B rows (plain stores,
// L3-absorbed). T = OUT/16 threads/edge (r16: latency-bound fix). 1/(deg+1) deferred to red.
template <int OUT>
__global__ __launch_bounds__(256) void feast_msg(
    const int* __restrict__ srcs, const int2* __restrict__ erec, int E,
    const _Float16* __restrict__ xwa, const _Float16* __restrict__ xuh,
    const float* __restrict__ cvec, _Float16* __restrict__ msg)
{
    constexpr int NC = NH * OUT, NCO = NC + OUT, LDR = NCO + 16;
    const int T = OUT / 16;
    size_t tid = (size_t)blockIdx.x * 256 + threadIdx.x;
    int e = (int)(tid / T);
    int ch = (int)(tid % T);
    if (e >= E) return;
    int s = srcs[e];
    int2 ed = erec[e];
    int d = ed.x, pd = ed.y;
    f16x8 u8s = *(const f16x8*)(xwa + (size_t)s * LDR + NCO);
    f16x2 u2s = *(const f16x2*)(xwa + (size_t)s * LDR + NCO + 8);
    f16x8 u8d = *(const f16x8*)(xuh + (size_t)d * QLD);
    f16x2 u2d = *(const f16x2*)(xuh + (size_t)d * QLD + 8);
    float t[NH];
    float m = -1e30f;
#pragma unroll
    for (int h = 0; h < 8; ++h) {
        t[h] = (float)u8s[h] - (float)u8d[h] + cvec[h];
        m = fmaxf(m, t[h]);
    }
    t[8] = (float)u2s[0] - (float)u2d[0] + cvec[8];
    m = fmaxf(m, t[8]);
    float den = 0.f;
#pragma unroll
    for (int h = 0; h < NH; ++h) { t[h] = __expf(t[h] - m); den += t[h]; }
    float sc = 1.f / den;

    const f16x8* xrow = (const f16x8*)(xwa + (size_t)s * LDR) + ch * 2;
    float acc[16] = {};
#pragma unroll
    for (int h = 0; h < NH; ++h) {
        float qh = t[h] * sc;
        f16x8 a = xrow[h * (OUT / 8)];
        f16x8 b = xrow[h * (OUT / 8) + 1];
#pragma unroll
        for (int j = 0; j < 8; ++j) {
            acc[j]     += qh * (float)a[j];
            acc[8 + j] += qh * (float)b[j];
        }
    }
    f16x8* mo = (f16x8*)(msg + (size_t)pd * OUT + ch * 16);
    f16x8 r0, r1;
#pragma unroll
    for (int j = 0; j < 8; ++j) {
        r0[j] = (_Float16)acc[j];
        r1[j] = (_Float16)acc[8 + j];
    }
    mo[0] = r0;
    mo[1] = r1;
}

// ---------------- Phase 2: contiguous CSR reduce, (sum+Wself)/(deg+1)+bias+act -> fp16 (+pool) ----------------
template <int OUT>
__global__ __launch_bounds__(256) void feast_red(
    const int* __restrict__ ds,
    const _Float16* __restrict__ msg, const _Float16* __restrict__ xwa,
    const float* __restrict__ bias, _Float16* __restrict__ outp,
    int n, int ldo, int col0, int act,
    const int* __restrict__ clust, float* __restrict__ pooled)
{
    constexpr int NC = NH * OUT, LDR = NC + OUT + 16;
    const int L = OUT / 8;
    size_t tid = (size_t)blockIdx.x * 256 + threadIdx.x;
    int d = (int)(tid / L);
    int p = (int)(tid % L);
    if (d >= n) return;
    int beg = ds[d];
    int end = ds[d + 1];
    int deg = end - beg;
    float acc[8] = {};
    int i = beg;
    for (; i + 4 <= end; i += 4) {  // 4 independent 16B loads in flight
        f16x8 v0 = *(const f16x8*)(msg + (size_t)i * OUT + p * 8);
        f16x8 v1 = *(const f16x8*)(msg + (size_t)(i + 1) * OUT + p * 8);
        f16x8 v2 = *(const f16x8*)(msg + (size_t)(i + 2) * OUT + p * 8);
        f16x8 v3 = *(const f16x8*)(msg + (size_t)(i + 3) * OUT + p * 8);
#pragma unroll
        for (int j = 0; j < 8; ++j)
            acc[j] += ((float)v0[j] + (float)v1[j]) + ((float)v2[j] + (float)v3[j]);
    }
    for (; i < end; ++i) {
        f16x8 v0 = *(const f16x8*)(msg + (size_t)i * OUT + p * 8);
#pragma unroll
        for (int j = 0; j < 8; ++j) acc[j] += (float)v0[j];
    }
    float sc = 1.f / (float)(deg + 1);
    f16x8 sv = *(const f16x8*)(xwa + (size_t)d * LDR + NC + p * 8);  // x*Wself
    float o[8];
    f16x8 oh;
#pragma unroll
    for (int j = 0; j < 8; ++j) {
        float v = (acc[j] + (float)sv[j]) * sc + bias[p * 8 + j];
        if (act) v = v > 0.f ? v : 0.1f * v;
        o[j] = v;
        oh[j] = (_Float16)v;
    }
    *(f16x8*)(outp + (size_t)d * ldo + col0 + p * 8) = oh;
    if (clust) {  // fused mean-pool accumulation (fp32, pre-quantization)
        float* pp = pooled + (size_t)clust[d] * OUT + p * 8;
#pragma unroll
        for (int j = 0; j < 8; ++j) unsafeAtomicAdd(&pp[j], o[j]);
    }
}

// ---------------- pooling divide ----------------
__global__ void pool_div(float* __restrict__ pooled, const int* __restrict__ pcnt, int C, int m)
{
    size_t tid = (size_t)blockIdx.x * 256 + threadIdx.x;
    int j = (int)(tid / C);
    if (j >= m) return;
    pooled[tid] /= fmaxf((float)pcnt[j], 1.f);
}

// ---------------- fc1 weight -> fp16 transposed [1024][32] ----------------
__global__ void w1_to_f16t(const float* __restrict__ w1, _Float16* __restrict__ w1t)
{
    int i = blockIdx.x * 256 + threadIdx.x;
    if (i >= 32 * 1024) return;
    int n = i >> 5, k = i & 31;
    w1t[i] = (_Float16)w1[k * 1024 + n];
}

// ---------------- fused FC head via f16 MFMA: lrelu(y@W1+b1)@W2+b2, row-normalize ----------------
__global__ __launch_bounds__(256) void fc_head2(
    const _Float16* __restrict__ yin, const _Float16* __restrict__ w1t,
    const float* __restrict__ b1, const float* __restrict__ w2,
    const float* __restrict__ b2, float* __restrict__ outp, int n)
{
    const int lane = threadIdx.x & 63, wv = threadIdx.x >> 6;
    const int g = lane >> 4, r16 = lane & 15;
    const int node0 = blockIdx.x * 64 + wv * 16;

    f16x8 afrag = {};
    int anode = node0 + r16;
    if (anode < n) afrag = *(const f16x8*)(yin + (size_t)anode * 32 + g * 8);

    float o0[4] = {0.f, 0.f, 0.f, 0.f};
    float o1[4] = {0.f, 0.f, 0.f, 0.f};
    float o2[4] = {0.f, 0.f, 0.f, 0.f};
    const f32x4 zero4 = {0.f, 0.f, 0.f, 0.f};

#pragma unroll 2
    for (int t = 0; t < 64; ++t) {
        const f16x8 bfrag = *(const f16x8*)(w1t + ((size_t)(t * 16 + r16)) * 32 + g * 8);
        f32x4 d = __builtin_amdgcn_mfma_f32_16x16x32_f16(afrag, bfrag, zero4, 0, 0, 0);
        int kh = t * 16 + r16;
        float b1v = b1[kh];
        float w20 = w2[kh * 3], w21 = w2[kh * 3 + 1], w22 = w2[kh * 3 + 2];
#pragma unroll
        for (int r = 0; r < 4; ++r) {
            float h = d[r] + b1v;
            h = h > 0.f ? h : 0.1f * h;
            o0[r] += h * w20;
            o1[r] += h * w21;
            o2[r] += h * w22;
        }
    }
#pragma unroll
    for (int r = 0; r < 4; ++r) {
#pragma unroll
        for (int off = 1; off < 16; off <<= 1) {
            o0[r] += __shfl_xor(o0[r], off);
            o1[r] += __shfl_xor(o1[r], off);
            o2[r] += __shfl_xor(o2[r], off);
        }
    }
    if (r16 == 0) {
#pragma unroll
        for (int r = 0; r < 4; ++r) {
            int node = node0 + g * 4 + r;
            if (node >= n) continue;
            float v0 = o0[r] + b2[0];
            float v1 = o1[r] + b2[1];
            float v2 = o2[r] + b2[2];
            float nr = fmaxf(sqrtf(v0 * v0 + v1 * v1 + v2 * v2), 1e-12f);
            outp[(size_t)node * 3 + 0] = v0 / nr;
            outp[(size_t)node * 3 + 1] = v1 / nr;
            outp[(size_t)node * 3 + 2] = v2 / nr;
        }
    }
}

// ---------------- dispatch helpers ----------------
static void launch_msg(int outC, const int* srcs, const int2* erec, int E,
                       const _Float16* xwa, const _Float16* xuh, const float* cvec,
                       _Float16* msg, hipStream_t stream)
{
    dim3 g(ceil_div((size_t)E * (outC / 16), 256));
    if (outC == 32)       feast_msg<32><<<g, 256, 0, stream>>>(srcs, erec, E, xwa, xuh, cvec, msg);
    else if (outC == 64)  feast_msg<64><<<g, 256, 0, stream>>>(srcs, erec, E, xwa, xuh, cvec, msg);
    else                  feast_msg<128><<<g, 256, 0, stream>>>(srcs, erec, E, xwa, xuh, cvec, msg);
}

static void launch_red(int outC, const int* ds,
                       const _Float16* msg, const _Float16* xwa, const float* bias,
                       _Float16* outp, int n, int ldo, int col0, int act,
                       const int* clust, float* pooled, hipStream_t stream)
{
    dim3 g(ceil_div((size_t)n * (outC / 8), 256));
    if (outC == 32)       feast_red<32><<<g, 256, 0, stream>>>(ds, msg, xwa, bias, outp, n, ldo, col0, act, clust, pooled);
    else if (outC == 64)  feast_red<64><<<g, 256, 0, stream>>>(ds, msg, xwa, bias, outp, n, ldo, col0, act, clust, pooled);
    else                  feast_red<128><<<g, 256, 0, stream>>>(ds, msg, xwa, bias, outp, n, ldo, col0, act, clust, pooled);
}

extern "C" void kernel_launch(void* const* d_in, const int* in_sizes, int n_in,
                              void* d_out, int out_size, void* d_ws, size_t ws_size,
                              hipStream_t stream)
{
    const float* x      = (const float*)d_in[0];
    const int*   ei1    = (const int*)d_in[1];
    const int*   ei2    = (const int*)d_in[2];
    const int*   ei3    = (const int*)d_in[3];
    const int*   clust2 = (const int*)d_in[4];
    const int*   clust3 = (const int*)d_in[5];
    const float* lp[8][4];
    for (int i = 0; i < 8; ++i)
        for (int j = 0; j < 4; ++j)
            lp[i][j] = (const float*)d_in[6 + i * 4 + j];  // l1..l4,r1..r4 x {u,c,w,b}
    const float* fc1_w = (const float*)d_in[38];
    const float* fc1_b = (const float*)d_in[39];
    const float* fc2_w = (const float*)d_in[40];
    const float* fc2_b = (const float*)d_in[41];
    float* out = (float*)d_out;

    static const int lK[8]   = {6, 32, 64, 128, 128, 128, 64, 64};
    static const int lOUT[8] = {32, 64, 128, 128, 64, 64, 32, 32};
    static const int lSH[3]  = {5, 3, 1};  // bucket shifts: ~3125 buckets per level
    const int NB1 = ceil_div(cN1, 1 << lSH[0]);
    const int NB2 = ceil_div(cN2, 1 << lSH[1]);
    const int NB3 = ceil_div(cN3, 1 << lSH[2]);

    // ---- workspace layout (~240 MB) ----
    char* ws = (char*)d_ws;
    size_t off = 0;
    auto alloc = [&](size_t b) { size_t p = off; off += (b + 255) & ~(size_t)255; return p; };
    _Float16* XWA = (_Float16*)(ws + alloc((size_t)cN1 * 336 * 2));  // 67.2 MB (max n*LDR)
    _Float16* MSG = (_Float16*)(ws + alloc((size_t)cE1 * 32 * 2));   // 76.8 MB
    _Float16* XUH = (_Float16*)(ws + alloc((size_t)cN1 * QLD * 2));  // 3.2 MB
    // fp16 activations
    _Float16* X1CAT = (_Float16*)(ws + alloc((size_t)cN1 * 64 * 2)); // 12.8 MB
    _Float16* X2CAT = (_Float16*)(ws + alloc((size_t)cN2 * 128 * 2));// 6.4 MB
    _Float16* X2B   = (_Float16*)(ws + alloc((size_t)cN2 * 64 * 2)); // 3.2 MB
    _Float16* X3    = (_Float16*)(ws + alloc((size_t)cN3 * 128 * 2));// 1.6 MB
    _Float16* YB    = (_Float16*)(ws + alloc((size_t)cN1 * 32 * 2)); // 6.4 MB
    // fp32 pooled buffers (GEMM A inputs)
    float* GATH = (float*)(ws + alloc((size_t)cN2 * 32 * 4));        // 3.2 MB
    float* P3   = (float*)(ws + alloc((size_t)cN3 * 64 * 4));        // 1.6 MB
    int* SRCS1 = (int*)(ws + alloc((size_t)cE1 * 4));
    int* SRCS2 = (int*)(ws + alloc((size_t)cE2 * 4));
    int* SRCS3 = (int*)(ws + alloc((size_t)cE3 * 4));
    int2* EREC1 = (int2*)(ws + alloc((size_t)cE1 * 8));
    int2* EREC2 = (int2*)(ws + alloc((size_t)cE2 * 8));
    int2* EREC3 = (int2*)(ws + alloc((size_t)cE3 * 8));
    int2* TMP = (int2*)(ws + alloc((size_t)cE1 * 8));                // 9.6 MB bin scratch
    // combined scan outputs per level: [doff(n) | soff+E(n)]; ds[n]=E acts as doff sentinel
    int* DS1 = (int*)(ws + alloc((size_t)2 * cN1 * 4));
    int* DS2 = (int*)(ws + alloc((size_t)2 * cN2 * 4));
    int* DS3 = (int*)(ws + alloc((size_t)2 * cN3 * 4));
    int* BOFF = (int*)(ws + alloc((size_t)4096 * 4));
    // zero-block, ONE memset: per level [dcnt|scnt|curs|curd|bcnt|bcur] + PC2 + PC3
    size_t zn = (size_t)4 * (cN1 + cN2 + cN3) + 2 * (NB1 + NB2 + NB3) + cN2 + cN3;
    int* ZBLK = (int*)(ws + alloc(zn * 4));
    int* CB1 = ZBLK;
    int* CURS1 = CB1 + 2 * cN1;
    int* CURD1 = CURS1 + cN1;
    int* BCNT1 = CURD1 + cN1;
    int* BCUR1 = BCNT1 + NB1;
    int* CB2 = BCUR1 + NB1;
    int* CURS2 = CB2 + 2 * cN2;
    int* CURD2 = CURS2 + cN2;
    int* BCNT2 = CURD2 + cN2;
    int* BCUR2 = BCNT2 + NB2;
    int* CB3 = BCUR2 + NB2;
    int* CURS3 = CB3 + 2 * cN3;
    int* CURD3 = CURS3 + cN3;
    int* BCNT3 = CURD3 + cN3;
    int* BCUR3 = BCNT3 + NB3;
    int* PC2 = BCUR3 + NB3;
    int* PC3 = PC2 + cN2;
    int* PART = (int*)(ws + alloc(1024 * 4));
    _Float16* W1T = (_Float16*)(ws + alloc((size_t)32 * 1024 * 2));
    // pre-packed B panels
    PackArgs pa;
    int ptot = 0;
    for (int i = 0; i < 8; ++i) {
        pa.W[i] = lp[i][2]; pa.c[i] = lp[i][1]; pa.u[i] = lp[i][0];
        pa.K[i] = lK[i]; pa.OUT[i] = lOUT[i];
        pa.Kpad[i] = (lK[i] + 31) & ~31;
        pa.base[i] = ptot;
        ptot += (NH * lOUT[i] + lOUT[i] + NH) * pa.Kpad[i];
    }
    pa.total = ptot;
    _Float16* WT = (_Float16*)(ws + alloc((size_t)ptot * 2));

    auto run_scan = [&](const int* in, int* outp, int n) {
        int nb = (n + 1023) / 1024;
        scan1<<<nb, 1024, 0, stream>>>(in, outp, nb > 1 ? PART : nullptr, n);
        if (nb > 1) {
            scan1<<<1, 1024, 0, stream>>>(PART, PART, nullptr, nb);
            scan_add<<<nb, 1024, 0, stream>>>(outp, PART, n);
        }
    };

    // ---- zero all counters in ONE memset ----
    hipMemsetAsync(ZBLK, 0, zn * 4, stream);

    // ---- per-level build: fused counts, scans, segment-fill, binned 2-pass scatter ----
    auto build = [&](const int* ei, int E, int n, int* cb, int* curs, int* curd,
                     int* bcnt, int* bcur, int nb, int shift, int* ds,
                     int* srcs, int2* erec) {
        count_b3<<<ceil_div(E, 256), 256, 0, stream>>>(ei, ei + E, E, cb + n, cb, bcnt, shift);
        run_scan(cb, ds, 2 * n);  // ds[0:n]=doff ; ds[n:2n]=soff+E (ds[n]=E sentinel)
        run_scan(bcnt, BOFF, nb);
        fill_src<<<ceil_div(n, 256), 256, 0, stream>>>(ds + n, cb + n, srcs, n, E);
        bin_pass1<<<ceil_div(E, 256), 256, 0, stream>>>(ei, ei + E, E, BOFF, bcur, TMP, shift);
        bin_pass2<<<ceil_div(E, 256), 256, 0, stream>>>(TMP, E, ds + n, curs, ds, curd, erec, E);
    };
    build(ei1, cE1, cN1, CB1, CURS1, CURD1, BCNT1, BCUR1, NB1, lSH[0], DS1, SRCS1, EREC1);
    build(ei2, cE2, cN2, CB2, CURS2, CURD2, BCNT2, BCUR2, NB2, lSH[1], DS2, SRCS2, EREC2);
    build(ei3, cE3, cN3, CB3, CURS3, CURD3, BCNT3, BCUR3, NB3, lSH[2], DS3, SRCS3, EREC3);

    // ---- pack all B panels (W|Wself|u, transposed fp16) + fc1 transpose ----
    pack_b_all<<<ceil_div(ptot, 256), 256, 0, stream>>>(pa, WT);
    w1_to_f16t<<<ceil_div(32 * 1024, 256), 256, 0, stream>>>(fc1_w, W1T);

    auto feast = [&](auto* xin, int ldx, const int* ridx, int n, int cin, int li,
                     const int* srcs, const int2* erec, const int* ds, int E,
                     _Float16* dstp, int ldo, int col0, int act,
                     const int* pclust, float* pooled) {
        int outC = lOUT[li];
        int NC = NH * outC;
        int N = NC + outC + NH;
        gemm_merged<<<dim3(ceil_div(N, 64), ceil_div(n, 64)), 256, 0, stream>>>(
            xin, ldx, ridx, WT + (size_t)pa.base[li], pa.Kpad[li], XWA, XUH, n, cin, NC, outC);
        launch_msg(outC, srcs, erec, E, XWA, XUH, lp[li][1], MSG, stream);
        launch_red(outC, ds, MSG, XWA, lp[li][3], dstp, n, ldo, col0, act, pclust, pooled, stream);
    };

    // l1: [N1,6] -> [N1,32] into X1CAT[:, 0:32]  (+fused pool into GATH)
    hipMemsetAsync(GATH, 0, (size_t)cN2 * 32 * 4, stream);
    count_idx<<<ceil_div(cN1, 256), 256, 0, stream>>>(clust2, cN1, PC2);
    feast(x, 6, nullptr, cN1, 6, 0, SRCS1, EREC1, DS1, cE1, X1CAT, 64, 0, 1, clust2, GATH);
    pool_div<<<ceil_div((size_t)cN2 * 32, 256), 256, 0, stream>>>(GATH, PC2, 32, cN2);

    // l2: [N2,32] -> [N2,64] into X2CAT[:, 0:64]  (+fused pool into P3)
    count_idx<<<ceil_div(cN2, 256), 256, 0, stream>>>(clust3, cN2, PC3);
    hipMemsetAsync(P3, 0, (size_t)cN3 * 64 * 4, stream);
    feast(GATH, 32, nullptr, cN2, 32, 1, SRCS2, EREC2, DS2, cE2, X2CAT, 128, 0, 1, clust3, P3);
    pool_div<<<ceil_div((size_t)cN3 * 64, 256), 256, 0, stream>>>(P3, PC3, 64, cN3);

    // l3: [N3,64] -> [N3,128] into X3
    feast(P3, 64, nullptr, cN3, 64, 2, SRCS3, EREC3, DS3, cE3, X3, 128, 0, 1, nullptr, nullptr);
    // l4: [N3,128] -> [N3,128] in-place (X3 consumed by gemm before red writes)
    feast(X3, 128, nullptr, cN3, 128, 3, SRCS3, EREC3, DS3, cE3, X3, 128, 0, 1, nullptr, nullptr);

    // r1: feast over unpooled x3 (gather fused via ridx=clust3) -> X2CAT[:, 64:128] (no act)
    feast(X3, 128, clust3, cN2, 128, 4, SRCS2, EREC2, DS2, cE2, X2CAT, 128, 64, 0, nullptr, nullptr);

    // r2: [N2,128] -> [N2,64] into X2B
    feast(X2CAT, 128, nullptr, cN2, 128, 5, SRCS2, EREC2, DS2, cE2, X2B, 64, 0, 1, nullptr, nullptr);

    // r3: feast over unpooled x2 (gather fused via ridx=clust2) -> X1CAT[:, 32:64] (no act)
    feast(X2B, 64, clust2, cN1, 64, 6, SRCS1, EREC1, DS1, cE1, X1CAT, 64, 32, 0, nullptr, nullptr);

    // r4: [N1,64] -> [N1,32] into YB
    feast(X1CAT, 64, nullptr, cN1, 64, 7, SRCS1, EREC1, DS1, cE1, YB, 32, 0, 1, nullptr, nullptr);

    // fused FC head + normalize (f16 MFMA)
    fc_head2<<<ceil_div(cN1, 64), 256, 0, stream>>>(YB, W1T, fc1_b, fc2_w, fc2_b, out, cN1);

    (void)in_sizes; (void)n_in; (void)out_size; (void)ws_size;
}

// Round 18
// 990.304 us; speedup vs baseline: 1.2706x; 1.2706x over previous
//
#include <hip/hip_runtime.h>
#include <cstddef>
#include <cstdint>

#define NH 9
#define QLD 16  // compact xu row stride in fp16 (32B, line-aligned rows)

typedef _Float16 f16x8 __attribute__((ext_vector_type(8)));
typedef _Float16 f16x4 __attribute__((ext_vector_type(4)));
typedef _Float16 f16x2 __attribute__((ext_vector_type(2)));
typedef float f32x4 __attribute__((ext_vector_type(4)));

static const int cN1 = 100000, cN2 = 25000, cN3 = 6250;
static const int cE1 = 1200000, cE2 = 300000, cE3 = 75000;

static inline unsigned ceil_div(size_t a, size_t b) { return (unsigned)((a + b - 1) / b); }

// ---------------- pre-packed B panel: WT[n][Kpad] fp16, cols = [W | Wself | u] ----------------
struct PackArgs {
    const float* W[8];
    const float* c[8];
    const float* u[8];
    int K[8], OUT[8], Kpad[8], base[8];
    int total;
};

__global__ void pack_b_all(PackArgs a, _Float16* __restrict__ wt)
{
    int i = blockIdx.x * 256 + threadIdx.x;
    if (i >= a.total) return;
    int li = 0;
#pragma unroll
    for (int j = 1; j < 8; ++j) li += (i >= a.base[j]);
    int r = i - a.base[li];
    int Kp = a.Kpad[li], K = a.K[li], OUT = a.OUT[li];
    int NC = NH * OUT, NCO = NC + OUT;
    int n = r / Kp, k = r % Kp;
    float v = 0.f;
    if (k < K) {
        if (n < NC) v = a.W[li][(size_t)k * NC + n];
        else if (n < NCO) {
            const float* cv = a.c[li];
            float t[NH], m = -1e30f;
#pragma unroll
            for (int h = 0; h < NH; ++h) { t[h] = cv[h]; m = fmaxf(m, t[h]); }
            float den = 0.f;
#pragma unroll
            for (int h = 0; h < NH; ++h) { t[h] = __expf(t[h] - m); den += t[h]; }
            int o = n - NC;
            float acc = 0.f;
#pragma unroll
            for (int h = 0; h < NH; ++h) acc += t[h] * a.W[li][(size_t)k * NC + h * OUT + o];
            v = acc / den;
        } else {
            v = a.u[li][(size_t)k * NH + (n - NCO)];
        }
    }
    wt[i] = (_Float16)v;
}

// ---------------- merged f16 MFMA GEMM: C row = [ xW (NC) | x*Wself (OUT) | xu (9) | pad ] ----------------
// A is fp32 or fp16 (template); fp16 path uses direct 16B loads -> conflict-free LDS staging.
// Optional ridx gathers A rows. xu tail also copied to compact XUH.
// Fragment layout verified numerically (fc_head2, rounds 3-16).
template <typename AT>
__global__ __launch_bounds__(256) void gemm_merged(
    const AT* __restrict__ A, int lda, const int* __restrict__ ridx,
    const _Float16* __restrict__ WT, int kpad,
    _Float16* __restrict__ C, _Float16* __restrict__ xuh,
    int M, int K, int NC, int OUT)
{
    const int N = NC + OUT + NH;
    const int NCO = NC + OUT;
    const int ldc = NCO + 16;
    const int BM = 64, BK = 32, LK = 40;
    __shared__ _Float16 As[BM][LK];
    __shared__ _Float16 Bs[64][LK];  // transposed: Bs[n][k]
    const int tid = threadIdx.x;
    const int row0 = blockIdx.y * BM, col0 = blockIdx.x * 64;
    const int lane = tid & 63, wv = tid >> 6;
    const int g = lane >> 4, r16 = lane & 15;
    const int wr = wv >> 1, wc = wv & 1;
    f32x4 acc[2][2] = {};
    for (int k0 = 0; k0 < K; k0 += BK) {
        if constexpr (sizeof(AT) == 2) {
            int r = tid >> 2, c0 = (tid & 3) * 8;
            int gr = row0 + r, gk = k0 + c0;
            f16x8 h = {};
            if (gr < M) {
                int ar = ridx ? ridx[gr] : gr;
                h = *(const f16x8*)((const _Float16*)A + (size_t)ar * lda + gk);
            }
            *(f16x8*)&As[r][c0] = h;
        } else {
            for (int l = tid; l < 512; l += 256) {
                int r = l >> 3, c0 = (l & 7) * 4;
                int gr = row0 + r, gk = k0 + c0;
                float v0 = 0.f, v1 = 0.f, v2 = 0.f, v3 = 0.f;
                if (gr < M) {
                    int ar = ridx ? ridx[gr] : gr;
                    const float* ap = (const float*)A + (size_t)ar * lda + gk;
                    if (gk < K)     v0 = ap[0];
                    if (gk + 1 < K) v1 = ap[1];
                    if (gk + 2 < K) v2 = ap[2];
                    if (gk + 3 < K) v3 = ap[3];
                }
                f16x4 h;
                h[0] = (_Float16)v0; h[1] = (_Float16)v1; h[2] = (_Float16)v2; h[3] = (_Float16)v3;
                *(f16x4*)&As[r][c0] = h;
            }
        }
        {
            int nn = tid >> 2, c0 = (tid & 3) * 8;
            int gn = col0 + nn, gk = k0 + c0;
            f16x8 h = {};
            if (gn < N) h = *(const f16x8*)(WT + (size_t)gn * kpad + gk);
            *(f16x8*)&Bs[nn][c0] = h;
        }
        __syncthreads();
        f16x8 af[2], bf[2];
#pragma unroll
        for (int i = 0; i < 2; ++i) af[i] = *(const f16x8*)&As[wr * 32 + i * 16 + r16][g * 8];
#pragma unroll
        for (int j = 0; j < 2; ++j) bf[j] = *(const f16x8*)&Bs[wc * 32 + j * 16 + r16][g * 8];
#pragma unroll
        for (int i = 0; i < 2; ++i)
#pragma unroll
            for (int j = 0; j < 2; ++j)
                acc[i][j] = __builtin_amdgcn_mfma_f32_16x16x32_f16(af[i], bf[j], acc[i][j], 0, 0, 0);
        __syncthreads();
    }
#pragma unroll
    for (int i = 0; i < 2; ++i)
#pragma unroll
        for (int j = 0; j < 2; ++j) {
            int gc = col0 + wc * 32 + j * 16 + r16;
            if (gc >= N) continue;
            int tcol = gc - NCO;
#pragma unroll
            for (int rr = 0; rr < 4; ++rr) {
                int gr = row0 + wr * 32 + i * 16 + g * 4 + rr;
                if (gr >= M) continue;
                _Float16 val = (_Float16)acc[i][j][rr];
                C[(size_t)gr * ldc + gc] = val;
                if (tcol >= 0) xuh[(size_t)gr * QLD + tcol] = val;
            }
        }
}

// ---------------- counting / scan / segment-fill / packed scatter ----------------
__global__ void count_idx(const int* __restrict__ idx, int n, int* __restrict__ cnt)
{
    int i = blockIdx.x * 256 + threadIdx.x;
    if (i < n) atomicAdd(&cnt[idx[i]], 1);
}

__global__ void count_both(const int* __restrict__ src, const int* __restrict__ dst, int E,
                           int* __restrict__ scnt, int* __restrict__ dcnt)
{
    int i = blockIdx.x * 256 + threadIdx.x;
    if (i >= E) return;
    atomicAdd(&scnt[src[i]], 1);
    atomicAdd(&dcnt[dst[i]], 1);
}

__global__ __launch_bounds__(1024) void scan1(const int* __restrict__ in, int* __restrict__ out,
                                              int* __restrict__ part, int n)
{
    __shared__ int wsum[16];
    const int tid = threadIdx.x, lane = tid & 63, wv = tid >> 6;
    int i = blockIdx.x * 1024 + tid;
    int v = (i < n) ? in[i] : 0;
    int acc = v;
#pragma unroll
    for (int off = 1; off < 64; off <<= 1) {
        int t = __shfl_up(acc, off);
        if (lane >= off) acc += t;
    }
    if (lane == 63) wsum[wv] = acc;
    __syncthreads();
    if (wv == 0 && lane < 16) {
        int s = wsum[lane];
        int a2 = s;
#pragma unroll
        for (int off = 1; off < 16; off <<= 1) {
            int t = __shfl_up(a2, off);
            if (lane >= off) a2 += t;
        }
        wsum[lane] = a2 - s;
    }
    __syncthreads();
    int ex = wsum[wv] + acc - v;
    if (i < n) out[i] = ex;
    if (part && tid == 1023) part[blockIdx.x] = ex + v;
}

__global__ void scan_add(int* __restrict__ out, const int* __restrict__ part, int n)
{
    int i = blockIdx.x * 1024 + threadIdx.x;
    if (i < n) out[i] += part[blockIdx.x];
}

__global__ void fill_src(const int* __restrict__ soffB, const int* __restrict__ scnt,
                         int* __restrict__ srcs, int n, int ebias)
{
    int i = blockIdx.x * 256 + threadIdx.x;
    if (i >= n) return;
    int b = soffB[i] - ebias, c = scnt[i];
    for (int k = 0; k < c; ++k) srcs[b + k] = i;
}

// ONE random 8B write per edge: erec[src-pos] = {dst, dst-CSR-slot}.
// Per-node counter atomics are ~12-way contention (cheap). r17 lesson: bucket-histogram
// atomics at ~400-way contention cost 2x more than the line-amplification they save.
__global__ void scatter_light(const int* __restrict__ src, const int* __restrict__ dst, int E,
                              const int* __restrict__ soffB, int* __restrict__ curs,
                              const int* __restrict__ doff, int* __restrict__ curd,
                              int2* __restrict__ erec, int ebias)
{
    int e = blockIdx.x * 256 + threadIdx.x;
    if (e >= E) return;
    int s = src[e], d = dst[e];
    int ps = soffB[s] - ebias + atomicAdd(&curs[s], 1);
    int pd = doff[d] + atomicAdd(&curd[d], 1);
    erec[ps] = make_int2(d, pd);
}

// ---------------- Phase 1: per-edge q (inline softmax) + 9-head collapse -> MSG[pd] ----------------
// src-sorted compute (xwa row L1-hot); MSG write random but full 64-256B rows (plain stores,
// L3-absorbed). T = OUT/16 threads/edge (r16: latency-bound fix). 1/(deg+1) deferred to red.
template <int OUT>
__global__ __launch_bounds__(256) void feast_msg(
    const int* __restrict__ srcs, const int2* __restrict__ erec, int E,
    const _Float16* __restrict__ xwa, const _Float16* __restrict__ xuh,
    const float* __restrict__ cvec, _Float16* __restrict__ msg)
{
    constexpr int NC = NH * OUT, NCO = NC + OUT, LDR = NCO + 16;
    const int T = OUT / 16;
    size_t tid = (size_t)blockIdx.x * 256 + threadIdx.x;
    int e = (int)(tid / T);
    int ch = (int)(tid % T);
    if (e >= E) return;
    int s = srcs[e];
    int2 ed = erec[e];
    int d = ed.x, pd = ed.y;
    f16x8 u8s = *(const f16x8*)(xwa + (size_t)s * LDR + NCO);
    f16x2 u2s = *(const f16x2*)(xwa + (size_t)s * LDR + NCO + 8);
    f16x8 u8d = *(const f16x8*)(xuh + (size_t)d * QLD);
    f16x2 u2d = *(const f16x2*)(xuh + (size_t)d * QLD + 8);
    float t[NH];
    float m = -1e30f;
#pragma unroll
    for (int h = 0; h < 8; ++h) {
        t[h] = (float)u8s[h] - (float)u8d[h] + cvec[h];
        m = fmaxf(m, t[h]);
    }
    t[8] = (float)u2s[0] - (float)u2d[0] + cvec[8];
    m = fmaxf(m, t[8]);
    float den = 0.f;
#pragma unroll
    for (int h = 0; h < NH; ++h) { t[h] = __expf(t[h] - m); den += t[h]; }
    float sc = 1.f / den;

    const f16x8* xrow = (const f16x8*)(xwa + (size_t)s * LDR) + ch * 2;
    float acc[16] = {};
#pragma unroll
    for (int h = 0; h < NH; ++h) {
        float qh = t[h] * sc;
        f16x8 a = xrow[h * (OUT / 8)];
        f16x8 b = xrow[h * (OUT / 8) + 1];
#pragma unroll
        for (int j = 0; j < 8; ++j) {
            acc[j]     += qh * (float)a[j];
            acc[8 + j] += qh * (float)b[j];
        }
    }
    f16x8* mo = (f16x8*)(msg + (size_t)pd * OUT + ch * 16);
    f16x8 r0, r1;
#pragma unroll
    for (int j = 0; j < 8; ++j) {
        r0[j] = (_Float16)acc[j];
        r1[j] = (_Float16)acc[8 + j];
    }
    mo[0] = r0;
    mo[1] = r1;
}

// ---------------- Phase 2: contiguous CSR reduce, (sum+Wself)/(deg+1)+bias+act -> fp16 (+pool) ----------------
template <int OUT>
__global__ __launch_bounds__(256) void feast_red(
    const int* __restrict__ ds,
    const _Float16* __restrict__ msg, const _Float16* __restrict__ xwa,
    const float* __restrict__ bias, _Float16* __restrict__ outp,
    int n, int ldo, int col0, int act,
    const int* __restrict__ clust, float* __restrict__ pooled)
{
    constexpr int NC = NH * OUT, LDR = NC + OUT + 16;
    const int L = OUT / 8;
    size_t tid = (size_t)blockIdx.x * 256 + threadIdx.x;
    int d = (int)(tid / L);
    int p = (int)(tid % L);
    if (d >= n) return;
    int beg = ds[d];
    int end = ds[d + 1];
    int deg = end - beg;
    float acc[8] = {};
    int i = beg;
    for (; i + 4 <= end; i += 4) {  // 4 independent 16B loads in flight
        f16x8 v0 = *(const f16x8*)(msg + (size_t)i * OUT + p * 8);
        f16x8 v1 = *(const f16x8*)(msg + (size_t)(i + 1) * OUT + p * 8);
        f16x8 v2 = *(const f16x8*)(msg + (size_t)(i + 2) * OUT + p * 8);
        f16x8 v3 = *(const f16x8*)(msg + (size_t)(i + 3) * OUT + p * 8);
#pragma unroll
        for (int j = 0; j < 8; ++j)
            acc[j] += ((float)v0[j] + (float)v1[j]) + ((float)v2[j] + (float)v3[j]);
    }
    for (; i < end; ++i) {
        f16x8 v0 = *(const f16x8*)(msg + (size_t)i * OUT + p * 8);
#pragma unroll
        for (int j = 0; j < 8; ++j) acc[j] += (float)v0[j];
    }
    float sc = 1.f / (float)(deg + 1);
    f16x8 sv = *(const f16x8*)(xwa + (size_t)d * LDR + NC + p * 8);  // x*Wself
    float o[8];
    f16x8 oh;
#pragma unroll
    for (int j = 0; j < 8; ++j) {
        float v = (acc[j] + (float)sv[j]) * sc + bias[p * 8 + j];
        if (act) v = v > 0.f ? v : 0.1f * v;
        o[j] = v;
        oh[j] = (_Float16)v;
    }
    *(f16x8*)(outp + (size_t)d * ldo + col0 + p * 8) = oh;
    if (clust) {  // fused mean-pool accumulation (fp32, pre-quantization)
        float* pp = pooled + (size_t)clust[d] * OUT + p * 8;
#pragma unroll
        for (int j = 0; j < 8; ++j) unsafeAtomicAdd(&pp[j], o[j]);
    }
}

// ---------------- pooling divide ----------------
__global__ void pool_div(float* __restrict__ pooled, const int* __restrict__ pcnt, int C, int m)
{
    size_t tid = (size_t)blockIdx.x * 256 + threadIdx.x;
    int j = (int)(tid / C);
    if (j >= m) return;
    pooled[tid] /= fmaxf((float)pcnt[j], 1.f);
}

// ---------------- fc1 weight -> fp16 transposed [1024][32] ----------------
__global__ void w1_to_f16t(const float* __restrict__ w1, _Float16* __restrict__ w1t)
{
    int i = blockIdx.x * 256 + threadIdx.x;
    if (i >= 32 * 1024) return;
    int n = i >> 5, k = i & 31;
    w1t[i] = (_Float16)w1[k * 1024 + n];
}

// ---------------- fused FC head via f16 MFMA: lrelu(y@W1+b1)@W2+b2, row-normalize ----------------
__global__ __launch_bounds__(256) void fc_head2(
    const _Float16* __restrict__ yin, const _Float16* __restrict__ w1t,
    const float* __restrict__ b1, const float* __restrict__ w2,
    const float* __restrict__ b2, float* __restrict__ outp, int n)
{
    const int lane = threadIdx.x & 63, wv = threadIdx.x >> 6;
    const int g = lane >> 4, r16 = lane & 15;
    const int node0 = blockIdx.x * 64 + wv * 16;

    f16x8 afrag = {};
    int anode = node0 + r16;
    if (anode < n) afrag = *(const f16x8*)(yin + (size_t)anode * 32 + g * 8);

    float o0[4] = {0.f, 0.f, 0.f, 0.f};
    float o1[4] = {0.f, 0.f, 0.f, 0.f};
    float o2[4] = {0.f, 0.f, 0.f, 0.f};
    const f32x4 zero4 = {0.f, 0.f, 0.f, 0.f};

#pragma unroll 2
    for (int t = 0; t < 64; ++t) {
        const f16x8 bfrag = *(const f16x8*)(w1t + ((size_t)(t * 16 + r16)) * 32 + g * 8);
        f32x4 d = __builtin_amdgcn_mfma_f32_16x16x32_f16(afrag, bfrag, zero4, 0, 0, 0);
        int kh = t * 16 + r16;
        float b1v = b1[kh];
        float w20 = w2[kh * 3], w21 = w2[kh * 3 + 1], w22 = w2[kh * 3 + 2];
#pragma unroll
        for (int r = 0; r < 4; ++r) {
            float h = d[r] + b1v;
            h = h > 0.f ? h : 0.1f * h;
            o0[r] += h * w20;
            o1[r] += h * w21;
            o2[r] += h * w22;
        }
    }
#pragma unroll
    for (int r = 0; r < 4; ++r) {
#pragma unroll
        for (int off = 1; off < 16; off <<= 1) {
            o0[r] += __shfl_xor(o0[r], off);
            o1[r] += __shfl_xor(o1[r], off);
            o2[r] += __shfl_xor(o2[r], off);
        }
    }
    if (r16 == 0) {
#pragma unroll
        for (int r = 0; r < 4; ++r) {
            int node = node0 + g * 4 + r;
            if (node >= n) continue;
            float v0 = o0[r] + b2[0];
            float v1 = o1[r] + b2[1];
            float v2 = o2[r] + b2[2];
            float nr = fmaxf(sqrtf(v0 * v0 + v1 * v1 + v2 * v2), 1e-12f);
            outp[(size_t)node * 3 + 0] = v0 / nr;
            outp[(size_t)node * 3 + 1] = v1 / nr;
            outp[(size_t)node * 3 + 2] = v2 / nr;
        }
    }
}

// ---------------- dispatch helpers ----------------
static void launch_msg(int outC, const int* srcs, const int2* erec, int E,
                       const _Float16* xwa, const _Float16* xuh, const float* cvec,
                       _Float16* msg, hipStream_t stream)
{
    dim3 g(ceil_div((size_t)E * (outC / 16), 256));
    if (outC == 32)       feast_msg<32><<<g, 256, 0, stream>>>(srcs, erec, E, xwa, xuh, cvec, msg);
    else if (outC == 64)  feast_msg<64><<<g, 256, 0, stream>>>(srcs, erec, E, xwa, xuh, cvec, msg);
    else                  feast_msg<128><<<g, 256, 0, stream>>>(srcs, erec, E, xwa, xuh, cvec, msg);
}

static void launch_red(int outC, const int* ds,
                       const _Float16* msg, const _Float16* xwa, const float* bias,
                       _Float16* outp, int n, int ldo, int col0, int act,
                       const int* clust, float* pooled, hipStream_t stream)
{
    dim3 g(ceil_div((size_t)n * (outC / 8), 256));
    if (outC == 32)       feast_red<32><<<g, 256, 0, stream>>>(ds, msg, xwa, bias, outp, n, ldo, col0, act, clust, pooled);
    else if (outC == 64)  feast_red<64><<<g, 256, 0, stream>>>(ds, msg, xwa, bias, outp, n, ldo, col0, act, clust, pooled);
    else                  feast_red<128><<<g, 256, 0, stream>>>(ds, msg, xwa, bias, outp, n, ldo, col0, act, clust, pooled);
}

extern "C" void kernel_launch(void* const* d_in, const int* in_sizes, int n_in,
                              void* d_out, int out_size, void* d_ws, size_t ws_size,
                              hipStream_t stream)
{
    const float* x      = (const float*)d_in[0];
    const int*   ei1    = (const int*)d_in[1];
    const int*   ei2    = (const int*)d_in[2];
    const int*   ei3    = (const int*)d_in[3];
    const int*   clust2 = (const int*)d_in[4];
    const int*   clust3 = (const int*)d_in[5];
    const float* lp[8][4];
    for (int i = 0; i < 8; ++i)
        for (int j = 0; j < 4; ++j)
            lp[i][j] = (const float*)d_in[6 + i * 4 + j];  // l1..l4,r1..r4 x {u,c,w,b}
    const float* fc1_w = (const float*)d_in[38];
    const float* fc1_b = (const float*)d_in[39];
    const float* fc2_w = (const float*)d_in[40];
    const float* fc2_b = (const float*)d_in[41];
    float* out = (float*)d_out;

    static const int lK[8]   = {6, 32, 64, 128, 128, 128, 64, 64};
    static const int lOUT[8] = {32, 64, 128, 128, 64, 64, 32, 32};

    // ---- workspace layout (~230 MB) ----
    char* ws = (char*)d_ws;
    size_t off = 0;
    auto alloc = [&](size_t b) { size_t p = off; off += (b + 255) & ~(size_t)255; return p; };
    _Float16* XWA = (_Float16*)(ws + alloc((size_t)cN1 * 336 * 2));  // 67.2 MB (max n*LDR)
    _Float16* MSG = (_Float16*)(ws + alloc((size_t)cE1 * 32 * 2));   // 76.8 MB
    _Float16* XUH = (_Float16*)(ws + alloc((size_t)cN1 * QLD * 2));  // 3.2 MB
    // fp16 activations
    _Float16* X1CAT = (_Float16*)(ws + alloc((size_t)cN1 * 64 * 2)); // 12.8 MB
    _Float16* X2CAT = (_Float16*)(ws + alloc((size_t)cN2 * 128 * 2));// 6.4 MB
    _Float16* X2B   = (_Float16*)(ws + alloc((size_t)cN2 * 64 * 2)); // 3.2 MB
    _Float16* X3    = (_Float16*)(ws + alloc((size_t)cN3 * 128 * 2));// 1.6 MB
    _Float16* YB    = (_Float16*)(ws + alloc((size_t)cN1 * 32 * 2)); // 6.4 MB
    // fp32 pooled buffers (GEMM A inputs)
    float* GATH = (float*)(ws + alloc((size_t)cN2 * 32 * 4));        // 3.2 MB
    float* P3   = (float*)(ws + alloc((size_t)cN3 * 64 * 4));        // 1.6 MB
    int* SRCS1 = (int*)(ws + alloc((size_t)cE1 * 4));
    int* SRCS2 = (int*)(ws + alloc((size_t)cE2 * 4));
    int* SRCS3 = (int*)(ws + alloc((size_t)cE3 * 4));
    int2* EREC1 = (int2*)(ws + alloc((size_t)cE1 * 8));
    int2* EREC2 = (int2*)(ws + alloc((size_t)cE2 * 8));
    int2* EREC3 = (int2*)(ws + alloc((size_t)cE3 * 8));
    // combined scan outputs per level: [doff(n) | soff+E(n)]; ds[n]=E acts as doff sentinel
    int* DS1 = (int*)(ws + alloc((size_t)2 * cN1 * 4));
    int* DS2 = (int*)(ws + alloc((size_t)2 * cN2 * 4));
    int* DS3 = (int*)(ws + alloc((size_t)2 * cN3 * 4));
    // zero-block, ONE memset: per level [dcnt|scnt|curs|curd] + PC2 + PC3
    size_t zn = (size_t)4 * (cN1 + cN2 + cN3) + cN2 + cN3;
    int* ZBLK = (int*)(ws + alloc(zn * 4));
    int* CB1 = ZBLK;
    int* CURS1 = CB1 + 2 * cN1;
    int* CURD1 = CURS1 + cN1;
    int* CB2 = CURD1 + cN1;
    int* CURS2 = CB2 + 2 * cN2;
    int* CURD2 = CURS2 + cN2;
    int* CB3 = CURD2 + cN2;
    int* CURS3 = CB3 + 2 * cN3;
    int* CURD3 = CURS3 + cN3;
    int* PC2 = CURD3 + cN3;
    int* PC3 = PC2 + cN2;
    int* PART = (int*)(ws + alloc(1024 * 4));
    _Float16* W1T = (_Float16*)(ws + alloc((size_t)32 * 1024 * 2));
    // pre-packed B panels
    PackArgs pa;
    int ptot = 0;
    for (int i = 0; i < 8; ++i) {
        pa.W[i] = lp[i][2]; pa.c[i] = lp[i][1]; pa.u[i] = lp[i][0];
        pa.K[i] = lK[i]; pa.OUT[i] = lOUT[i];
        pa.Kpad[i] = (lK[i] + 31) & ~31;
        pa.base[i] = ptot;
        ptot += (NH * lOUT[i] + lOUT[i] + NH) * pa.Kpad[i];
    }
    pa.total = ptot;
    _Float16* WT = (_Float16*)(ws + alloc((size_t)ptot * 2));

    auto run_scan = [&](const int* in, int* outp, int n) {
        int nb = (n + 1023) / 1024;
        scan1<<<nb, 1024, 0, stream>>>(in, outp, nb > 1 ? PART : nullptr, n);
        if (nb > 1) {
            scan1<<<1, 1024, 0, stream>>>(PART, PART, nullptr, nb);
            scan_add<<<nb, 1024, 0, stream>>>(outp, PART, n);
        }
    };

    // ---- zero all counters in ONE memset ----
    hipMemsetAsync(ZBLK, 0, zn * 4, stream);

    // ---- per-level build: fused counts, ONE combined scan, segment-fill, packed 8B scatter ----
    auto build = [&](const int* ei, int E, int n, int* cb, int* curs, int* curd, int* ds,
                     int* srcs, int2* erec) {
        count_both<<<ceil_div(E, 256), 256, 0, stream>>>(ei, ei + E, E, cb + n, cb);
        run_scan(cb, ds, 2 * n);  // ds[0:n]=doff ; ds[n:2n]=soff+E (ds[n]=E sentinel)
        fill_src<<<ceil_div(n, 256), 256, 0, stream>>>(ds + n, cb + n, srcs, n, E);
        scatter_light<<<ceil_div(E, 256), 256, 0, stream>>>(ei, ei + E, E, ds + n, curs, ds, curd, erec, E);
    };
    build(ei1, cE1, cN1, CB1, CURS1, CURD1, DS1, SRCS1, EREC1);
    build(ei2, cE2, cN2, CB2, CURS2, CURD2, DS2, SRCS2, EREC2);
    build(ei3, cE3, cN3, CB3, CURS3, CURD3, DS3, SRCS3, EREC3);

    // ---- pack all B panels (W|Wself|u, transposed fp16) + fc1 transpose ----
    pack_b_all<<<ceil_div(ptot, 256), 256, 0, stream>>>(pa, WT);
    w1_to_f16t<<<ceil_div(32 * 1024, 256), 256, 0, stream>>>(fc1_w, W1T);

    auto feast = [&](auto* xin, int ldx, const int* ridx, int n, int cin, int li,
                     const int* srcs, const int2* erec, const int* ds, int E,
                     _Float16* dstp, int ldo, int col0, int act,
                     const int* pclust, float* pooled) {
        int outC = lOUT[li];
        int NC = NH * outC;
        int N = NC + outC + NH;
        gemm_merged<<<dim3(ceil_div(N, 64), ceil_div(n, 64)), 256, 0, stream>>>(
            xin, ldx, ridx, WT + (size_t)pa.base[li], pa.Kpad[li], XWA, XUH, n, cin, NC, outC);
        launch_msg(outC, srcs, erec, E, XWA, XUH, lp[li][1], MSG, stream);
        launch_red(outC, ds, MSG, XWA, lp[li][3], dstp, n, ldo, col0, act, pclust, pooled, stream);
    };

    // l1: [N1,6] -> [N1,32] into X1CAT[:, 0:32]  (+fused pool into GATH)
    hipMemsetAsync(GATH, 0, (size_t)cN2 * 32 * 4, stream);
    count_idx<<<ceil_div(cN1, 256), 256, 0, stream>>>(clust2, cN1, PC2);
    feast(x, 6, nullptr, cN1, 6, 0, SRCS1, EREC1, DS1, cE1, X1CAT, 64, 0, 1, clust2, GATH);
    pool_div<<<ceil_div((size_t)cN2 * 32, 256), 256, 0, stream>>>(GATH, PC2, 32, cN2);

    // l2: [N2,32] -> [N2,64] into X2CAT[:, 0:64]  (+fused pool into P3)
    count_idx<<<ceil_div(cN2, 256), 256, 0, stream>>>(clust3, cN2, PC3);
    hipMemsetAsync(P3, 0, (size_t)cN3 * 64 * 4, stream);
    feast(GATH, 32, nullptr, cN2, 32, 1, SRCS2, EREC2, DS2, cE2, X2CAT, 128, 0, 1, clust3, P3);
    pool_div<<<ceil_div((size_t)cN3 * 64, 256), 256, 0, stream>>>(P3, PC3, 64, cN3);

    // l3: [N3,64] -> [N3,128] into X3
    feast(P3, 64, nullptr, cN3, 64, 2, SRCS3, EREC3, DS3, cE3, X3, 128, 0, 1, nullptr, nullptr);
    // l4: [N3,128] -> [N3,128] in-place (X3 consumed by gemm before red writes)
    feast(X3, 128, nullptr, cN3, 128, 3, SRCS3, EREC3, DS3, cE3, X3, 128, 0, 1, nullptr, nullptr);

    // r1: feast over unpooled x3 (gather fused via ridx=clust3) -> X2CAT[:, 64:128] (no act)
    feast(X3, 128, clust3, cN2, 128, 4, SRCS2, EREC2, DS2, cE2, X2CAT, 128, 64, 0, nullptr, nullptr);

    // r2: [N2,128] -> [N2,64] into X2B
    feast(X2CAT, 128, nullptr, cN2, 128, 5, SRCS2, EREC2, DS2, cE2, X2B, 64, 0, 1, nullptr, nullptr);

    // r3: feast over unpooled x2 (gather fused via ridx=clust2) -> X1CAT[:, 32:64] (no act)
    feast(X2B, 64, clust2, cN1, 64, 6, SRCS1, EREC1, DS1, cE1, X1CAT, 64, 32, 0, nullptr, nullptr);

    // r4: [N1,64] -> [N1,32] into YB
    feast(X1CAT, 64, nullptr, cN1, 64, 7, SRCS1, EREC1, DS1, cE1, YB, 32, 0, 1, nullptr, nullptr);

    // fused FC head + normalize (f16 MFMA)
    fc_head2<<<ceil_div(cN1, 64), 256, 0, stream>>>(YB, W1T, fc1_b, fc2_w, fc2_b, out, cN1);

    (void)in_sizes; (void)n_in; (void)out_size; (void)ws_size;
}